// Round 15
// baseline (472.229 us; speedup 1.0000x reference)
//
#include <hip/hip_runtime.h>
#include <math.h>

#define Bn 8192
#define Dn 512
#define Hn 256
#define TEMP_INV 0.5f

typedef __attribute__((ext_vector_type(8))) short short8;
typedef __attribute__((ext_vector_type(8))) unsigned short ushort8;
typedef __attribute__((ext_vector_type(4))) float f32x4;
typedef __attribute__((ext_vector_type(4))) int iv4;
typedef __attribute__((ext_vector_type(8))) int iv8;

__device__ __forceinline__ int swz(int x) { return x ^ ((x >> 3) & 0x70); }

__device__ __forceinline__ unsigned short f2bf(float f) {
  unsigned u = __builtin_bit_cast(unsigned, f);
  u += 0x7FFF + ((u >> 16) & 1);
  return (unsigned short)(u >> 16);
}
__device__ __forceinline__ float bf2f(unsigned short s) {
  unsigned u = ((unsigned)s) << 16;
  return __builtin_bit_cast(float, u);
}
__device__ __forceinline__ int pk4fp8(float a, float b, float c, float d) {
  int r = __builtin_amdgcn_cvt_pk_fp8_f32(a, b, 0, 0);
  r = __builtin_amdgcn_cvt_pk_fp8_f32(c, d, r, 1);
  return r;
}
__device__ __forceinline__ void gload16(const void* g, void* l) {
  __builtin_amdgcn_global_load_lds(
      (const __attribute__((address_space(1))) unsigned int*)g,
      (__attribute__((address_space(3))) unsigned int*)l, 16, 0, 0);
}

// Wbt arena (bytes): L0 = 8 dblk x 16 kk x 12 e x 4KB (kk=15 zeros); L1/L2 = 8 x 8 x 12 x 4KB
#define WBT_L1_OFF 6291456
#define WBT_L2_OFF 9437184

// ============ weight convert (ALL layers): fp32 (e,k,d) -> fp8 K=64 tiles, x16 ============
__global__ __launch_bounds__(256) void conv_w_all(
    const float* __restrict__ Wt0, const float* __restrict__ Ws0,
    const float* __restrict__ Wt1, const float* __restrict__ Ws1,
    const float* __restrict__ Wt2, const float* __restrict__ Ws2,
    unsigned char* __restrict__ Wbt) {
  __shared__ float T[64][65];
  int layer = blockIdx.z / 12, e = blockIdx.z - layer * 12;
  int IN = (layer == 0) ? 960 : 512;
  int NK = IN / 64;
  int NKP = (layer == 0) ? 16 : 8;
  int kk = blockIdx.x;
  int dblk = blockIdx.y;
  size_t obase = (layer == 0) ? 0 : (layer == 1) ? (size_t)WBT_L1_OFF : (size_t)WBT_L2_OFF;
  int t = threadIdx.x;
  if (kk >= NK) {
    if (layer == 0 && kk == 15) {  // zero pad tile
      iv4 z = {0, 0, 0, 0};
      *(iv4*)(Wbt + obase + (((size_t)(dblk * NKP + 15) * 12 + e) << 12) + t * 16) = z;
    }
    return;
  }
  const float* Wtl = (layer == 0) ? Wt0 : (layer == 1) ? Wt1 : Wt2;
  const float* Wsl = (layer == 0) ? Ws0 : (layer == 1) ? Ws1 : Ws2;
  const float* base = (e < 8) ? (Wtl + (size_t)e * IN * Dn) : (Wsl + (size_t)(e - 8) * IN * Dn);
  int k = t >> 2, dg = t & 3;
  const float* gp = base + (size_t)(kk * 64 + k) * Dn + dblk * 64 + dg * 16;
#pragma unroll
  for (int i = 0; i < 4; ++i) {
    float4 v = *(const float4*)(gp + i * 4);
    T[dg * 16 + i * 4 + 0][k] = v.x;
    T[dg * 16 + i * 4 + 1][k] = v.y;
    T[dg * 16 + i * 4 + 2][k] = v.z;
    T[dg * 16 + i * 4 + 3][k] = v.w;
  }
  __syncthreads();
  int col = t >> 2, gq = t & 3;
  int g = gq ^ ((col >> 1) & 3);
  const float* Tc = T[col];
  int4 o;
  o.x = pk4fp8(Tc[g * 8 + 0] * 16.f, Tc[g * 8 + 1] * 16.f, Tc[g * 8 + 2] * 16.f, Tc[g * 8 + 3] * 16.f);
  o.y = pk4fp8(Tc[g * 8 + 4] * 16.f, Tc[g * 8 + 5] * 16.f, Tc[g * 8 + 6] * 16.f, Tc[g * 8 + 7] * 16.f);
  o.z = pk4fp8(Tc[32 + g * 8 + 0] * 16.f, Tc[32 + g * 8 + 1] * 16.f, Tc[32 + g * 8 + 2] * 16.f, Tc[32 + g * 8 + 3] * 16.f);
  o.w = pk4fp8(Tc[32 + g * 8 + 4] * 16.f, Tc[32 + g * 8 + 5] * 16.f, Tc[32 + g * 8 + 6] * 16.f, Tc[32 + g * 8 + 7] * 16.f);
  *(int4*)(Wbt + obase + (((size_t)(dblk * NKP + kk) * 12 + e) << 12) + t * 16) = o;
}

// ============ gate-weight convert (ALL layers) ============
__global__ __launch_bounds__(64) void conv_wg_all(
    const float* __restrict__ Wg0, const float* __restrict__ Wg1,
    const float* __restrict__ Wg2, unsigned short* __restrict__ out) {
  int layer = blockIdx.z;
  int IN = (layer == 0) ? 960 : 512;
  int i = blockIdx.x * 64 + threadIdx.x;
  if (i >= IN) return;
  int e = blockIdx.y;
  int t = e >> 3, eg = e & 7;
  const float* Wg = (layer == 0) ? Wg0 : (layer == 1) ? Wg1 : Wg2;
  size_t off = (layer == 0) ? 0 : (layer == 1) ? (size_t)16 * 960 : (size_t)16 * 960 + 16 * 512;
  out[off + (size_t)e * IN + i] = f2bf(Wg[((size_t)t * IN + i) * 8 + eg]);
}

// ============ tower-weight convert (bf16) ============
template <int K, int H>
__global__ __launch_bounds__(256) void conv_tw(const float* __restrict__ W,
                                               unsigned short* __restrict__ out) {
  __shared__ float T[64][33];
  int kk = blockIdx.x, hb = blockIdx.y, t = blockIdx.z;
  int tid = threadIdx.x;
  const float* base = W + (size_t)t * K * H;
  int k = tid >> 3, dq = tid & 7;
  const float* gp = base + (size_t)(kk * 32 + k) * H + hb * 64 + dq * 8;
  float4 v0 = *(const float4*)gp, v1 = *(const float4*)(gp + 4);
  T[dq * 8 + 0][k] = v0.x; T[dq * 8 + 1][k] = v0.y; T[dq * 8 + 2][k] = v0.z; T[dq * 8 + 3][k] = v0.w;
  T[dq * 8 + 4][k] = v1.x; T[dq * 8 + 5][k] = v1.y; T[dq * 8 + 6][k] = v1.z; T[dq * 8 + 7][k] = v1.w;
  __syncthreads();
  int L = tid * 16;
  int nat = swz(L);
  int c = nat >> 6, k0 = (nat & 63) >> 1;
  ushort8 o;
#pragma unroll
  for (int u = 0; u < 8; ++u) o[u] = f2bf(T[c][k0 + u]);
  const int NHB = H / 64;
  *(ushort8*)(out + (((size_t)(kk * NHB + hb) * 2 + t) << 11) + (L >> 1)) = o;
}

// ============ embedding + FUSED gate0: 4 rows/block (+x0t pad-tile zeroing) ============
__global__ __launch_bounds__(256) void embed_kernel(
    const int* __restrict__ sparse, const float* __restrict__ dense,
    const float* __restrict__ emb, const float* __restrict__ dW,
    const float* __restrict__ db, const unsigned short* __restrict__ wgb0,
    const float* __restrict__ bg0,
    unsigned short* __restrict__ xn, unsigned char* __restrict__ xt,
    float* __restrict__ gates) {
  int b0 = blockIdx.x * 4, t = threadIdx.x;
  __shared__ float dfs[4][10];
  __shared__ __align__(16) unsigned short xrow[4][960];
  if (t < 40) dfs[t / 10][t % 10] = dense[(b0 + t / 10) * 10 + t % 10];
  __syncthreads();
  if (t < 240) {
    int c = t * 4;
#pragma unroll 1
    for (int r = 0; r < 4; ++r) {
      int b = b0 + r;
      float v[4];
      if (c < 640) {
        int f = c >> 5, e0 = c & 31;
        int idx = sparse[b * 20 + f];
        const float* ep = emb + ((size_t)f * 1000 + idx) * 32 + e0;
        float4 q = *(const float4*)ep;
        v[0] = q.x; v[1] = q.y; v[2] = q.z; v[3] = q.w;
      } else {
        int j = c - 640;
#pragma unroll
        for (int u = 0; u < 4; ++u) {
          float a = db[j + u];
#pragma unroll
          for (int d = 0; d < 10; ++d) a += dfs[r][d] * dW[d * 320 + j + u];
          v[u] = a;
        }
      }
      ushort4 pk;
      pk.x = f2bf(v[0]); pk.y = f2bf(v[1]); pk.z = f2bf(v[2]); pk.w = f2bf(v[3]);
      *(ushort4*)(xn + (size_t)b * 960 + c) = pk;
      *(ushort4*)(&xrow[r][c]) = pk;
      int col = b & 63;
      int lc = c & 63;
      int ks = lc >> 5, g = (lc & 31) >> 3, j0 = lc & 7;
      int gq = g ^ ((col >> 1) & 3);
      int pos = (col << 6) + (gq << 4) + (ks << 3) + j0;
      int p8 = pk4fp8(v[0] * 16.f, v[1] * 16.f, v[2] * 16.f, v[3] * 16.f);
      *(int*)(xt + (((size_t)(c >> 6) * 128 + (b >> 6)) << 12) + pos) = p8;
    }
  }
  // zero x0t pad tile (kk=15) for these 4 rows
  if (t < 16) {
    int rr = t >> 2, ch = t & 3;
    int b = b0 + rr;
    iv4 z = {0, 0, 0, 0};
    *(iv4*)(xt + (((size_t)(15 * 128 + (b >> 6))) << 12) + (b & 63) * 64 + ch * 16) = z;
  }
  __syncthreads();
  // ---- fused gate0 ----
  int r = t >> 6, lane = t & 63;
  int e = lane & 15, slice = lane >> 4;
  const unsigned short* xr = &xrow[r][slice * 240];
  const unsigned short* wr = wgb0 + (size_t)e * 960 + slice * 240;
  float p = 0.f;
#pragma unroll 2
  for (int i = 0; i < 240; i += 8) {
    short8 xv = *(const short8*)(xr + i);
    short8 wv2 = *(const short8*)(wr + i);
#pragma unroll
    for (int u = 0; u < 8; ++u)
      p += bf2f((unsigned short)xv[u]) * bf2f((unsigned short)wv2[u]);
  }
  p += __shfl_xor(p, 16);
  p += __shfl_xor(p, 32);
  float z = (p + bg0[e]) * TEMP_INV;
  float m = z;
  m = fmaxf(m, __shfl_xor(m, 1)); m = fmaxf(m, __shfl_xor(m, 2)); m = fmaxf(m, __shfl_xor(m, 4));
  float ex = expf(z - m);
  float s = ex;
  s += __shfl_xor(s, 1); s += __shfl_xor(s, 2); s += __shfl_xor(s, 4);
  if (lane < 16) gates[(size_t)(b0 + r) * 16 + lane] = ex / s;
}

// ============ gates (layers 1/2) ============
template <int IN>
__global__ __launch_bounds__(256) void gate_kernel(
    const unsigned short* __restrict__ x, const unsigned short* __restrict__ wgb,
    const float* __restrict__ bg, float* __restrict__ gates) {
  int tid = threadIdx.x;
  int wv = tid >> 6, lane = tid & 63;
  int b = blockIdx.x * 4 + wv;
  int e = lane & 15, slice = lane >> 4;
  const unsigned short* xr = x + (size_t)b * IN + slice * (IN / 4);
  const unsigned short* wr = wgb + (size_t)e * IN + slice * (IN / 4);
  float p = 0.f;
#pragma unroll 2
  for (int i = 0; i < IN / 4; i += 8) {
    short8 xv = *(const short8*)(xr + i);
    short8 wv2 = *(const short8*)(wr + i);
#pragma unroll
    for (int u = 0; u < 8; ++u)
      p += bf2f((unsigned short)xv[u]) * bf2f((unsigned short)wv2[u]);
  }
  p += __shfl_xor(p, 16);
  p += __shfl_xor(p, 32);
  int t = e >> 3, eg = e & 7;
  float z = (p + bg[t * 8 + eg]) * TEMP_INV;
  float m = z;
  m = fmaxf(m, __shfl_xor(m, 1)); m = fmaxf(m, __shfl_xor(m, 2)); m = fmaxf(m, __shfl_xor(m, 4));
  float ex = expf(z - m);
  float s = ex;
  s += __shfl_xor(s, 1); s += __shfl_xor(s, 2); s += __shfl_xor(s, 4);
  if (lane < 16) gates[(size_t)b * 16 + lane] = ex / s;
}

// ============ fused PLE layer: MX-scaled fp8 K=128 MFMA, 3-buffer ring ============
// LDS = 3 x 53248. Epilogue aliases: exchange->buf0, outs->buf1, gates->buf2.
#define STG 53248

template <int NKP, int MODE>
__global__ __launch_bounds__(768, 3) void ple_mfma(
    const unsigned char* __restrict__ xt, const float* __restrict__ gates,
    const unsigned char* __restrict__ Wbt,
    const float* __restrict__ btb, const float* __restrict__ bsh,
    unsigned short* __restrict__ outn, unsigned char* __restrict__ outt8,
    unsigned short* __restrict__ outtb) {
  __shared__ __align__(16) char smem[3 * STG];
  int tid = threadIdx.x;
  int wv = tid >> 6, lane = tid & 63;
  int r = lane & 15, g = lane >> 4;
  int s = blockIdx.x;
  int dblk = s & 7, bblk = s >> 3;
  int b0 = bblk * 64, d0 = dblk * 64;

  f32x4 acc[4][4];
#pragma unroll
  for (int i = 0; i < 4; ++i)
#pragma unroll
    for (int j = 0; j < 4; ++j) acc[i][j] = f32x4{0.f, 0.f, 0.f, 0.f};

  const unsigned char* xchunk = xt + ((size_t)bblk << 12);
  const unsigned char* wchunk = Wbt + (size_t)dblk * NKP * 49152;

  auto stage = [&](int t, char* lb) {
    const unsigned char* ws = wchunk + (size_t)t * 49152;
#pragma unroll
    for (int i = 0; i < 4; ++i)
      gload16(ws + tid * 16 + i * 12288, lb + tid * 16 + i * 12288);
    if (tid < 256)
      gload16(xchunk + (size_t)t * (128 * 4096) + tid * 16, lb + 49152 + tid * 16);
  };

  const int NS = NKP / 2;
  stage(0, smem);
  stage(1, smem + STG);

  for (int i = 0; i < NS; ++i) {
    if (i > 0) stage(2 * i + 1, smem + ((2 * i + 1) % 3) * STG);
    asm volatile("s_waitcnt vmcnt(0)" ::: "memory");
    __builtin_amdgcn_s_barrier();
    if (2 * i + 2 < NKP) stage(2 * i + 2, smem + ((2 * i + 2) % 3) * STG);
    {
      const char* lbE = smem + ((2 * i) % 3) * STG;
      const char* lbO = smem + ((2 * i + 1) % 3) * STG;
      const char* xbE = lbE + 49152;
      const char* xbO = lbO + 49152;
      const char* wbE = lbE + (wv << 12);
      const char* wbO = lbO + (wv << 12);
      int base = (r << 6) + ((g ^ ((r >> 1) & 3)) << 4);
      iv8 A[4];
#pragma unroll
      for (int rt = 0; rt < 4; ++rt) {
        iv4 lo = *(const iv4*)(xbE + rt * 1024 + base);
        iv4 hi = *(const iv4*)(xbO + rt * 1024 + base);
        A[rt] = __builtin_shufflevector(lo, hi, 0, 1, 2, 3, 4, 5, 6, 7);
      }
#pragma unroll
      for (int ct = 0; ct < 4; ++ct) {
        iv4 lo = *(const iv4*)(wbE + ct * 1024 + base);
        iv4 hi = *(const iv4*)(wbO + ct * 1024 + base);
        iv8 Bf = __builtin_shufflevector(lo, hi, 0, 1, 2, 3, 4, 5, 6, 7);
#pragma unroll
        for (int rt = 0; rt < 4; ++rt)
          acc[rt][ct] = __builtin_amdgcn_mfma_scale_f32_16x16x128_f8f6f4(
              A[rt], Bf, acc[rt][ct], 0, 0, 0, 127, 0, 127);
      }
    }
    __builtin_amdgcn_s_barrier();
  }
  __syncthreads();  // K-loop done; buffers become epilogue regions

  // gates -> buf2
  if (tid < 256)
    *(float4*)(smem + 2 * STG + tid * 16) = *(const float4*)(gates + (size_t)b0 * 16 + tid * 4);

  // ---- epilogue 1: dequant(1/256) + bias + relu -> fp8(x16) exchange (buf0) ----
  {
    const float* bp = (wv < 8) ? (btb + wv * Dn) : (bsh + (wv - 8) * Dn);
    float bias[4];
#pragma unroll
    for (int ct = 0; ct < 4; ++ct) bias[ct] = bp[d0 + ct * 16 + r];
    char* ex = smem + (wv << 12);
#pragma unroll
    for (int rt = 0; rt < 4; ++rt)
#pragma unroll
      for (int ct = 0; ct < 4; ++ct) {
        float v0 = fmaxf(acc[rt][ct][0] * 0.00390625f + bias[ct], 0.f) * 16.f;
        float v1 = fmaxf(acc[rt][ct][1] * 0.00390625f + bias[ct], 0.f) * 16.f;
        float v2 = fmaxf(acc[rt][ct][2] * 0.00390625f + bias[ct], 0.f) * 16.f;
        float v3 = fmaxf(acc[rt][ct][3] * 0.00390625f + bias[ct], 0.f) * 16.f;
        int col = ct * 16 + r;
        int off = (col << 6) + rt * 16 + g * 4;
        off ^= (col & 7) << 3;
        *(int*)(ex + off) = pk4fp8(v0, v1, v2, v3);
      }
  }
  __syncthreads();

  // ---- epilogue 2: gated combine (outs -> buf1) ----
  if (tid < 512) {
    int col = tid & 63, q = tid >> 6;
    int exoff = ((col << 6) + (q << 3)) ^ ((col & 7) << 3);
    long v[12];
#pragma unroll
    for (int e = 0; e < 12; ++e)
      v[e] = *(const long*)(smem + (e << 12) + exoff);
    unsigned short* os0 = (unsigned short*)(smem + STG);
    unsigned short* os1 = os0 + 64 * 72;
#pragma unroll
    for (int half = 0; half < 2; ++half) {
#pragma unroll
      for (int jj = 0; jj < 4; ++jj) {
        int row = (q << 3) + half * 4 + jj;
        const float* gp = (const float*)(smem + 2 * STG + (row << 6));
        float4 ga = ((const float4*)gp)[0];
        float4 gb = ((const float4*)gp)[1];
        float4 gc = ((const float4*)gp)[2];
        float4 gd = ((const float4*)gp)[3];
        float f[12];
#pragma unroll
        for (int e = 0; e < 12; ++e) {
          unsigned w32 = (unsigned)(v[e] >> (half * 32));
          f[e] = __builtin_amdgcn_cvt_f32_fp8((int)(w32 >> (jj * 8)), 0);
        }
        float s0 = ga.x * f[0] + ga.y * f[1] + ga.z * f[2] + ga.w * f[3] +
                   gb.x * f[8] + gb.y * f[9] + gb.z * f[10] + gb.w * f[11];
        float s1 = gc.x * f[4] + gc.y * f[5] + gc.z * f[6] + gc.w * f[7] +
                   gd.x * f[8] + gd.y * f[9] + gd.z * f[10] + gd.w * f[11];
        os0[row * 72 + col] = f2bf(s0 * 0.0625f);
        os1[row * 72 + col] = f2bf(s1 * 0.0625f);
      }
    }
  }
  __syncthreads();

  // ---- epilogue 3: global writes ----
  if (tid < 512) {
    int row = tid >> 3, cq = tid & 7;
    const unsigned short* os0 = (const unsigned short*)(smem + STG) + row * 72 + cq * 8;
    const unsigned short* os1 = os0 + 64 * 72;
    ushort8 p0 = *(const ushort8*)os0, p1 = *(const ushort8*)os1;
    int b = b0 + row, d = d0 + cq * 8;
    if (MODE == 0) {
      float m[8];
      ushort8 pk;
#pragma unroll
      for (int u = 0; u < 8; ++u) {
        m[u] = 0.5f * (bf2f((unsigned short)p0[u]) + bf2f((unsigned short)p1[u]));
        pk[u] = f2bf(m[u]);
      }
      *(ushort8*)(outn + (size_t)b * Dn + d) = pk;
      int lk = d & 63;
      int ks = lk >> 5, g2 = (lk & 31) >> 3;
      int gq = g2 ^ ((row >> 1) & 3);
      int pos = (row << 6) + (gq << 4) + (ks << 3);
      int2 o8;
      o8.x = pk4fp8(m[0] * 16.f, m[1] * 16.f, m[2] * 16.f, m[3] * 16.f);
      o8.y = pk4fp8(m[4] * 16.f, m[5] * 16.f, m[6] * 16.f, m[7] * 16.f);
      *(int2*)(outt8 + (((size_t)dblk * 128 + bblk) << 12) + pos) = o8;
    } else {
      int kk2 = d >> 5;
      int nat = (row << 6) + ((d & 31) << 1);
      *(ushort8*)(outtb + (((size_t)(0 * 16 + kk2) * 128 + bblk) << 11) + (swz(nat) >> 1)) = p0;
      *(ushort8*)(outtb + (((size_t)(1 * 16 + kk2) * 128 + bblk) << 11) + (swz(nat) >> 1)) = p1;
    }
  }
}

// ============ fused MFMA tower (bf16) ============
#define TWBUF 36864
#define H1OFF 73728

__global__ __launch_bounds__(512) void tower_mfma(
    const unsigned short* __restrict__ toutT,
    const unsigned short* __restrict__ twbt1, const unsigned short* __restrict__ twbt2,
    const float* __restrict__ tb1,
    const float* __restrict__ bng, const float* __restrict__ bnb,
    const float* __restrict__ bnm, const float* __restrict__ bnv,
    const float* __restrict__ tb2, const float* __restrict__ tw3,
    const float* __restrict__ tb3, float* __restrict__ out) {
  __shared__ __align__(16) char smem[106496];
  int tid = threadIdx.x;
  int wv = tid >> 6, lane = tid & 63, r = lane & 15, g = lane >> 4;
  int blk = blockIdx.x;
  int bblk = blk >> 1, sub = blk & 1;
  int b0 = blk * 32;
  char* h1t = smem + H1OFF;

  int t1 = wv >> 2, hb = wv & 3;
  f32x4 acc[2][4];
#pragma unroll
  for (int i = 0; i < 2; ++i)
#pragma unroll
    for (int j = 0; j < 4; ++j) acc[i][j] = f32x4{0.f, 0.f, 0.f, 0.f};

  auto stage1 = [&](int t, char* lb) {
#pragma unroll
    for (int i = 0; i < 4; ++i)
      gload16((const char*)twbt1 + (size_t)t * 32768 + tid * 16 + i * 8192,
              lb + tid * 16 + i * 8192);
    if (tid < 256) {
      int tt = tid >> 7, off = (tid & 127) * 16;
      gload16((const char*)toutT + (((size_t)(tt * 16 + t) * 128 + bblk) << 12) + sub * 2048 + off,
              lb + 32768 + tt * 2048 + off);
    }
  };

  stage1(0, smem);
  __syncthreads();
  int cur = 0;
  for (int kk = 0; kk < 16; ++kk) {
    if (kk + 1 < 16) stage1(kk + 1, smem + (cur ^ 1) * TWBUF);
    {
      const char* lb = smem + cur * TWBUF;
      const char* wb = lb + (hb * 2 + t1) * 4096;
      const char* xb = lb + 32768 + t1 * 2048;
      short8 a[2], bfr[4];
#pragma unroll
      for (int rt = 0; rt < 2; ++rt)
        a[rt] = *(const short8*)(xb + swz(((rt * 16 + r) << 6) + (g << 4)));
#pragma unroll
      for (int ct = 0; ct < 4; ++ct)
        bfr[ct] = *(const short8*)(wb + swz(((ct * 16 + r) << 6) + (g << 4)));
#pragma unroll
      for (int rt = 0; rt < 2; ++rt)
#pragma unroll
        for (int ct = 0; ct < 4; ++ct)
          acc[rt][ct] = __builtin_amdgcn_mfma_f32_16x16x32_bf16(a[rt], bfr[ct], acc[rt][ct], 0, 0, 0);
    }
    __syncthreads();
    cur ^= 1;
  }

  {
#pragma unroll
    for (int ct = 0; ct < 4; ++ct) {
      int h = hb * 64 + ct * 16 + r;
      int idx = t1 * 256 + h;
      float inv = rsqrtf(bnv[idx] + 1e-5f) * bng[idx];
      float mu = bnm[idx], be = bnb[idx], bias = tb1[idx];
      int kk2 = h >> 5, kloc = h & 31;
      char* tile = h1t + (t1 * 8 + kk2) * 2048;
#pragma unroll
      for (int rt = 0; rt < 2; ++rt)
#pragma unroll
        for (int j = 0; j < 4; ++j) {
          int lr = rt * 16 + g * 4 + j;
          float v = acc[rt][ct][j] + bias;
          v = (v - mu) * inv + be;
          v = fmaxf(v, 0.f);
          *(unsigned short*)(tile + swz((lr << 6) + (kloc << 1))) = f2bf(v);
        }
    }
  }
  __syncthreads();

  float* h2x = (float*)smem;
  if (wv < 4) {
    int t2 = wv >> 1, hb2 = wv & 1;
    f32x4 acc2[2][4];
#pragma unroll
    for (int i = 0; i < 2; ++i)
#pragma unroll
      for (int j = 0; j < 4; ++j) acc2[i][j] = f32x4{0.f, 0.f, 0.f, 0.f};
    for (int kk = 0; kk < 8; ++kk) {
      const char* xb = h1t + (t2 * 8 + kk) * 2048;
      const char* wb = (const char*)twbt2 + ((kk * 2 + hb2) * 2 + t2) * 4096;
      short8 a[2], bfr[4];
#pragma unroll
      for (int rt = 0; rt < 2; ++rt)
        a[rt] = *(const short8*)(xb + swz(((rt * 16 + r) << 6) + (g << 4)));
#pragma unroll
      for (int ct = 0; ct < 4; ++ct)
        bfr[ct] = *(const short8*)(wb + swz(((ct * 16 + r) << 6) + (g << 4)));
#pragma unroll
      for (int rt = 0; rt < 2; ++rt)
#pragma unroll
        for (int ct = 0; ct < 4; ++ct)
          acc2[rt][ct] = __builtin_amdgcn_mfma_f32_16x16x32_bf16(a[rt], bfr[ct], acc2[rt][ct], 0, 0, 0);
    }
#pragma unroll
    for (int ct = 0; ct < 4; ++ct) {
      int col = hb2 * 64 + ct * 16 + r;
      float bias = tb2[t2 * 128 + col];
#pragma unroll
      for (int rt = 0; rt < 2; ++rt)
#pragma unroll
        for (int j = 0; j < 4; ++j) {
          int lr = rt * 16 + g * 4 + j;
          h2x[(t2 * 32 + lr) * 129 + col] = fmaxf(acc2[rt][ct][j] + bias, 0.f);
        }
    }
  }
  __syncthreads();

  float* lgs = (float*)(smem + 40960);
  if (tid < 64) {
    int t3 = tid >> 5, lr = tid & 31;
    const float* hr = h2x + (t3 * 32 + lr) * 129;
    const float* w3 = tw3 + t3 * 128;
    float s = 0.f;
#pragma unroll 8
    for (int i = 0; i < 128; ++i) s += hr[i] * w3[i];
    lgs[t3 * 32 + lr] = s + tb3[t3];
  }
  __syncthreads();
  if (tid < 32) {
    int b = b0 + tid;
    float ctr = 1.f / (1.f + expf(-lgs[tid]));
    float cvr = 1.f / (1.f + expf(-lgs[32 + tid]));
    float cc = ctr * cvr;
    out[b] = ctr;
    out[Bn + b] = cc;
    out[2 * Bn + b] = cc;
  }
}

// ============ launch ============
extern "C" void kernel_launch(void* const* d_in, const int* in_sizes, int n_in,
                              void* d_out, int out_size, void* d_ws, size_t ws_size,
                              hipStream_t stream) {
  const int* sparse   = (const int*)d_in[0];
  const float* dense  = (const float*)d_in[1];
  const float* emb    = (const float*)d_in[2];
  const float* dW     = (const float*)d_in[3];
  const float* db     = (const float*)d_in[4];
  const float* Wt[3]  = {(const float*)d_in[5],  (const float*)d_in[11], (const float*)d_in[17]};
  const float* btb[3] = {(const float*)d_in[6],  (const float*)d_in[12], (const float*)d_in[18]};
  const float* Wsh[3] = {(const float*)d_in[7],  (const float*)d_in[13], (const float*)d_in[19]};
  const float* bsh[3] = {(const float*)d_in[8],  (const float*)d_in[14], (const float*)d_in[20]};
  const float* Wg[3]  = {(const float*)d_in[9],  (const float*)d_in[15], (const float*)d_in[21]};
  const float* bg[3]  = {(const float*)d_in[10], (const float*)d_in[16], (const float*)d_in[22]};
  const float* tw1 = (const float*)d_in[23];
  const float* tb1 = (const float*)d_in[24];
  const float* bng = (const float*)d_in[25];
  const float* bnb = (const float*)d_in[26];
  const float* bnm = (const float*)d_in[27];
  const float* bnv = (const float*)d_in[28];
  const float* tw2 = (const float*)d_in[29];
  const float* tb2 = (const float*)d_in[30];
  const float* tw3 = (const float*)d_in[31];
  const float* tb3 = (const float*)d_in[32];

  // workspace layout
  unsigned short* x0n = (unsigned short*)d_ws;                    // bf16 8192x960
  unsigned short* x1n = x0n + (size_t)Bn * 960;                   // bf16 8192x512
  unsigned short* toutT = x1n + (size_t)Bn * 512;                 // bf16 tower tiles
  float* gatesB = (float*)(toutT + (size_t)Bn * 1024);            // f32 8192x16
  unsigned short* twbt1 = (unsigned short*)(gatesB + (size_t)Bn * 16);
  unsigned short* twbt2 = twbt1 + (size_t)2 * 512 * 256;
  unsigned char* x0t = (unsigned char*)(twbt2 + (size_t)2 * 256 * 128);  // fp8 8192x1024 (padded)
  unsigned char* x1t = x0t + (size_t)Bn * 1024;                   // fp8 8192x512
  unsigned char* Wbt = x1t + (size_t)Bn * 512;                    // fp8 tiles, 3 layers (12.6MB)
  unsigned short* wgb = (unsigned short*)(Wbt + (size_t)12582912);
  unsigned short* wgb0 = wgb;
  unsigned short* wgb1 = wgb0 + (size_t)16 * 960;
  unsigned short* wgb2 = wgb1 + (size_t)16 * 512;
  unsigned short* x2n = x0n;
  unsigned char* x2t = x0t;

  conv_tw<512, 256><<<dim3(16, 4, 2), 256, 0, stream>>>(tw1, twbt1);
  conv_tw<256, 128><<<dim3(8, 2, 2), 256, 0, stream>>>(tw2, twbt2);
  conv_wg_all<<<dim3(15, 16, 3), 64, 0, stream>>>(Wg[0], Wg[1], Wg[2], wgb);
  conv_w_all<<<dim3(16, 8, 36), 256, 0, stream>>>(Wt[0], Wsh[0], Wt[1], Wsh[1],
                                                  Wt[2], Wsh[2], Wbt);

  embed_kernel<<<Bn / 4, 256, 0, stream>>>(sparse, dense, emb, dW, db, wgb0, bg[0],
                                           x0n, x0t, gatesB);
  ple_mfma<16, 0><<<1024, 768, 0, stream>>>(x0t, gatesB, Wbt, btb[0], bsh[0], x1n, x1t, nullptr);

  gate_kernel<512><<<Bn / 4, 256, 0, stream>>>(x1n, wgb1, bg[1], gatesB);
  ple_mfma<8, 0><<<1024, 768, 0, stream>>>(x1t, gatesB, Wbt + WBT_L1_OFF, btb[1], bsh[1],
                                           x2n, x2t, nullptr);

  gate_kernel<512><<<Bn / 4, 256, 0, stream>>>(x2n, wgb2, bg[2], gatesB);
  ple_mfma<8, 1><<<1024, 768, 0, stream>>>(x2t, gatesB, Wbt + WBT_L2_OFF, btb[2], bsh[2],
                                           nullptr, nullptr, toutT);

  tower_mfma<<<256, 512, 0, stream>>>(toutT, twbt1, twbt2, tb1, bng, bnb, bnm, bnv,
                                      tb2, tw3, tb3, (float*)d_out);
}

// Round 16
// 294.109 us; speedup vs baseline: 1.6056x; 1.6056x over previous
//
#include <hip/hip_runtime.h>
#include <math.h>

#define Bn 8192
#define INP0 960
#define Dn 512
#define Hn 256
#define TEMP_INV 0.5f

typedef __attribute__((ext_vector_type(8))) short short8;
typedef __attribute__((ext_vector_type(8))) unsigned short ushort8;
typedef __attribute__((ext_vector_type(4))) float f32x4;
typedef __attribute__((ext_vector_type(2))) long lx2;

__device__ __forceinline__ int swz(int x) { return x ^ ((x >> 3) & 0x70); }

__device__ __forceinline__ unsigned short f2bf(float f) {
  unsigned u = __builtin_bit_cast(unsigned, f);
  u += 0x7FFF + ((u >> 16) & 1);
  return (unsigned short)(u >> 16);
}
__device__ __forceinline__ float bf2f(unsigned short s) {
  unsigned u = ((unsigned)s) << 16;
  return __builtin_bit_cast(float, u);
}
__device__ __forceinline__ int pk4fp8(float a, float b, float c, float d) {
  int r = __builtin_amdgcn_cvt_pk_fp8_f32(a, b, 0, 0);
  r = __builtin_amdgcn_cvt_pk_fp8_f32(c, d, r, 1);
  return r;
}
__device__ __forceinline__ void gload16(const void* g, void* l) {
  __builtin_amdgcn_global_load_lds(
      (const __attribute__((address_space(1))) unsigned int*)g,
      (__attribute__((address_space(3))) unsigned int*)l, 16, 0, 0);
}

// Wbt arena offsets (bytes): L0 15*8*12*4KB, L1/L2 8*8*12*4KB
#define WBT_L1_OFF 5898240
#define WBT_L2_OFF 9043968

// ============ weight convert (ALL layers): fp32 (e,k,d) -> fp8 K=64 tiles, x16 ============
__global__ __launch_bounds__(256) void conv_w_all(
    const float* __restrict__ Wt0, const float* __restrict__ Ws0,
    const float* __restrict__ Wt1, const float* __restrict__ Ws1,
    const float* __restrict__ Wt2, const float* __restrict__ Ws2,
    unsigned char* __restrict__ Wbt) {
  __shared__ float T[64][65];
  int layer = blockIdx.z / 12, e = blockIdx.z - layer * 12;
  int IN = (layer == 0) ? 960 : 512;
  int NK = IN / 64;
  int kk = blockIdx.x;
  if (kk >= NK) return;
  int dblk = blockIdx.y;
  const float* Wtl = (layer == 0) ? Wt0 : (layer == 1) ? Wt1 : Wt2;
  const float* Wsl = (layer == 0) ? Ws0 : (layer == 1) ? Ws1 : Ws2;
  size_t obase = (layer == 0) ? 0 : (layer == 1) ? (size_t)WBT_L1_OFF : (size_t)WBT_L2_OFF;
  int t = threadIdx.x;
  const float* base = (e < 8) ? (Wtl + (size_t)e * IN * Dn) : (Wsl + (size_t)(e - 8) * IN * Dn);
  int k = t >> 2, dg = t & 3;
  const float* gp = base + (size_t)(kk * 64 + k) * Dn + dblk * 64 + dg * 16;
#pragma unroll
  for (int i = 0; i < 4; ++i) {
    float4 v = *(const float4*)(gp + i * 4);
    T[dg * 16 + i * 4 + 0][k] = v.x;
    T[dg * 16 + i * 4 + 1][k] = v.y;
    T[dg * 16 + i * 4 + 2][k] = v.z;
    T[dg * 16 + i * 4 + 3][k] = v.w;
  }
  __syncthreads();
  int col = t >> 2, gq = t & 3;
  int g = gq ^ ((col >> 1) & 3);
  const float* Tc = T[col];
  int4 o;
  o.x = pk4fp8(Tc[g * 8 + 0] * 16.f, Tc[g * 8 + 1] * 16.f, Tc[g * 8 + 2] * 16.f, Tc[g * 8 + 3] * 16.f);
  o.y = pk4fp8(Tc[g * 8 + 4] * 16.f, Tc[g * 8 + 5] * 16.f, Tc[g * 8 + 6] * 16.f, Tc[g * 8 + 7] * 16.f);
  o.z = pk4fp8(Tc[32 + g * 8 + 0] * 16.f, Tc[32 + g * 8 + 1] * 16.f, Tc[32 + g * 8 + 2] * 16.f, Tc[32 + g * 8 + 3] * 16.f);
  o.w = pk4fp8(Tc[32 + g * 8 + 4] * 16.f, Tc[32 + g * 8 + 5] * 16.f, Tc[32 + g * 8 + 6] * 16.f, Tc[32 + g * 8 + 7] * 16.f);
  *(int4*)(Wbt + obase + (((size_t)(dblk * NK + kk) * 12 + e) << 12) + t * 16) = o;
}

// ============ gate-weight convert (ALL layers): fp32 (t,IN,8) -> bf16 rows [e][IN] ============
__global__ __launch_bounds__(64) void conv_wg_all(
    const float* __restrict__ Wg0, const float* __restrict__ Wg1,
    const float* __restrict__ Wg2, unsigned short* __restrict__ out) {
  int layer = blockIdx.z;
  int IN = (layer == 0) ? 960 : 512;
  int i = blockIdx.x * 64 + threadIdx.x;
  if (i >= IN) return;
  int e = blockIdx.y;
  int t = e >> 3, eg = e & 7;
  const float* Wg = (layer == 0) ? Wg0 : (layer == 1) ? Wg1 : Wg2;
  size_t off = (layer == 0) ? 0 : (layer == 1) ? (size_t)16 * 960 : (size_t)16 * 960 + 16 * 512;
  out[off + (size_t)e * IN + i] = f2bf(Wg[((size_t)t * IN + i) * 8 + eg]);
}

// ============ tower-weight convert (bf16) ============
template <int K, int H>
__global__ __launch_bounds__(256) void conv_tw(const float* __restrict__ W,
                                               unsigned short* __restrict__ out) {
  __shared__ float T[64][33];
  int kk = blockIdx.x, hb = blockIdx.y, t = blockIdx.z;
  int tid = threadIdx.x;
  const float* base = W + (size_t)t * K * H;
  int k = tid >> 3, dq = tid & 7;
  const float* gp = base + (size_t)(kk * 32 + k) * H + hb * 64 + dq * 8;
  float4 v0 = *(const float4*)gp, v1 = *(const float4*)(gp + 4);
  T[dq * 8 + 0][k] = v0.x; T[dq * 8 + 1][k] = v0.y; T[dq * 8 + 2][k] = v0.z; T[dq * 8 + 3][k] = v0.w;
  T[dq * 8 + 4][k] = v1.x; T[dq * 8 + 5][k] = v1.y; T[dq * 8 + 6][k] = v1.z; T[dq * 8 + 7][k] = v1.w;
  __syncthreads();
  int L = tid * 16;
  int nat = swz(L);
  int c = nat >> 6, k0 = (nat & 63) >> 1;
  ushort8 o;
#pragma unroll
  for (int u = 0; u < 8; ++u) o[u] = f2bf(T[c][k0 + u]);
  const int NHB = H / 64;
  *(ushort8*)(out + (((size_t)(kk * NHB + hb) * 2 + t) << 11) + (L >> 1)) = o;
}

// ============ embedding + FUSED gate0: 4 rows/block ============
__global__ __launch_bounds__(256) void embed_kernel(
    const int* __restrict__ sparse, const float* __restrict__ dense,
    const float* __restrict__ emb, const float* __restrict__ dW,
    const float* __restrict__ db, const unsigned short* __restrict__ wgb0,
    const float* __restrict__ bg0,
    unsigned short* __restrict__ xn, unsigned char* __restrict__ xt,
    float* __restrict__ gates) {
  int b0 = blockIdx.x * 4, t = threadIdx.x;
  __shared__ float dfs[4][10];
  __shared__ __align__(16) unsigned short xrow[4][960];
  if (t < 40) dfs[t / 10][t % 10] = dense[(b0 + t / 10) * 10 + t % 10];
  __syncthreads();
  if (t < 240) {
    int c = t * 4;
#pragma unroll 1
    for (int r = 0; r < 4; ++r) {
      int b = b0 + r;
      float v[4];
      if (c < 640) {
        int f = c >> 5, e0 = c & 31;
        int idx = sparse[b * 20 + f];
        const float* ep = emb + ((size_t)f * 1000 + idx) * 32 + e0;
        float4 q = *(const float4*)ep;
        v[0] = q.x; v[1] = q.y; v[2] = q.z; v[3] = q.w;
      } else {
        int j = c - 640;
#pragma unroll
        for (int u = 0; u < 4; ++u) {
          float a = db[j + u];
#pragma unroll
          for (int d = 0; d < 10; ++d) a += dfs[r][d] * dW[d * 320 + j + u];
          v[u] = a;
        }
      }
      ushort4 pk;
      pk.x = f2bf(v[0]); pk.y = f2bf(v[1]); pk.z = f2bf(v[2]); pk.w = f2bf(v[3]);
      *(ushort4*)(xn + (size_t)b * 960 + c) = pk;
      *(ushort4*)(&xrow[r][c]) = pk;
      int col = b & 63;
      int lc = c & 63;
      int ks = lc >> 5, g = (lc & 31) >> 3, j0 = lc & 7;
      int gq = g ^ ((col >> 1) & 3);
      int pos = (col << 6) + (gq << 4) + (ks << 3) + j0;
      int p8 = pk4fp8(v[0] * 16.f, v[1] * 16.f, v[2] * 16.f, v[3] * 16.f);
      *(int*)(xt + (((size_t)(c >> 6) * 128 + (b >> 6)) << 12) + pos) = p8;
    }
  }
  __syncthreads();
  // ---- fused gate0 ----
  int r = t >> 6, lane = t & 63;
  int e = lane & 15, slice = lane >> 4;
  const unsigned short* xr = &xrow[r][slice * 240];
  const unsigned short* wr = wgb0 + (size_t)e * 960 + slice * 240;
  float p = 0.f;
#pragma unroll 2
  for (int i = 0; i < 240; i += 8) {
    short8 xv = *(const short8*)(xr + i);
    short8 wv2 = *(const short8*)(wr + i);
#pragma unroll
    for (int u = 0; u < 8; ++u)
      p += bf2f((unsigned short)xv[u]) * bf2f((unsigned short)wv2[u]);
  }
  p += __shfl_xor(p, 16);
  p += __shfl_xor(p, 32);
  float z = (p + bg0[e]) * TEMP_INV;
  float m = z;
  m = fmaxf(m, __shfl_xor(m, 1)); m = fmaxf(m, __shfl_xor(m, 2)); m = fmaxf(m, __shfl_xor(m, 4));
  float ex = expf(z - m);
  float s = ex;
  s += __shfl_xor(s, 1); s += __shfl_xor(s, 2); s += __shfl_xor(s, 4);
  if (lane < 16) gates[(size_t)(b0 + r) * 16 + lane] = ex / s;
}

// ============ gates (layers 1/2): bf16 weight rows + short8 loads ============
template <int IN>
__global__ __launch_bounds__(256) void gate_kernel(
    const unsigned short* __restrict__ x, const unsigned short* __restrict__ wgb,
    const float* __restrict__ bg, float* __restrict__ gates) {
  int tid = threadIdx.x;
  int wv = tid >> 6, lane = tid & 63;
  int b = blockIdx.x * 4 + wv;
  int e = lane & 15, slice = lane >> 4;
  const unsigned short* xr = x + (size_t)b * IN + slice * (IN / 4);
  const unsigned short* wr = wgb + (size_t)e * IN + slice * (IN / 4);
  float p = 0.f;
#pragma unroll 2
  for (int i = 0; i < IN / 4; i += 8) {
    short8 xv = *(const short8*)(xr + i);
    short8 wv2 = *(const short8*)(wr + i);
#pragma unroll
    for (int u = 0; u < 8; ++u)
      p += bf2f((unsigned short)xv[u]) * bf2f((unsigned short)wv2[u]);
  }
  p += __shfl_xor(p, 16);
  p += __shfl_xor(p, 32);
  int t = e >> 3, eg = e & 7;
  float z = (p + bg[t * 8 + eg]) * TEMP_INV;
  float m = z;
  m = fmaxf(m, __shfl_xor(m, 1)); m = fmaxf(m, __shfl_xor(m, 2)); m = fmaxf(m, __shfl_xor(m, 4));
  float ex = expf(z - m);
  float s = ex;
  s += __shfl_xor(s, 1); s += __shfl_xor(s, 2); s += __shfl_xor(s, 4);
  if (lane < 16) gates[(size_t)b * 16 + lane] = ex / s;
}

// ============ fused PLE layer: fp8 MFMA, K=64 steps, b128 LDS reads, dbuf (R12) ============
#define GSH 0
#define OUTS 4096
#define SB 22528
#define STG 53248

template <int IN, int MODE>
__global__ __launch_bounds__(768, 3) void ple_mfma(
    const unsigned char* __restrict__ xt, const float* __restrict__ gates,
    const unsigned char* __restrict__ Wbt,
    const float* __restrict__ btb, const float* __restrict__ bsh,
    unsigned short* __restrict__ outn, unsigned char* __restrict__ outt8,
    unsigned short* __restrict__ outtb) {
  __shared__ __align__(16) char smem[129024];
  const int NK = IN / 64;
  int tid = threadIdx.x;
  int wv = tid >> 6, lane = tid & 63;
  int r = lane & 15, g = lane >> 4;
  int s = blockIdx.x;
  int dblk = s & 7, bblk = s >> 3;
  int b0 = bblk * 64, d0 = dblk * 64;

  if (tid < 256)
    *(float4*)(smem + GSH + tid * 16) = *(const float4*)(gates + (size_t)b0 * 16 + tid * 4);

  f32x4 acc[4][4];
#pragma unroll
  for (int i = 0; i < 4; ++i)
#pragma unroll
    for (int j = 0; j < 4; ++j) acc[i][j] = f32x4{0.f, 0.f, 0.f, 0.f};

  const unsigned char* xchunk = xt + ((size_t)bblk << 12);
  const unsigned char* wchunk = Wbt + (size_t)(dblk * NK) * 49152;

  auto stage = [&](int t, char* lb) {
    const unsigned char* ws = wchunk + (size_t)t * 49152;
#pragma unroll
    for (int i = 0; i < 4; ++i)
      gload16(ws + tid * 16 + i * 12288, lb + tid * 16 + i * 12288);
    if (tid < 256)
      gload16(xchunk + (size_t)t * (128 * 4096) + tid * 16, lb + 49152 + tid * 16);
  };

  stage(0, smem + SB);

  for (int kk = 0; kk < NK; ++kk) {
    asm volatile("s_waitcnt vmcnt(0)" ::: "memory");
    __builtin_amdgcn_s_barrier();
    if (kk + 1 < NK) stage(kk + 1, smem + SB + ((kk + 1) & 1) * STG);
    {
      const char* lb = smem + SB + (kk & 1) * STG;
      const char* xb = lb + 49152;
      const char* wb = lb + (wv << 12);
      int base = (r << 6) + ((g ^ ((r >> 1) & 3)) << 4);
      lx2 A[4], B[4];
#pragma unroll
      for (int rt = 0; rt < 4; ++rt) A[rt] = *(const lx2*)(xb + rt * 1024 + base);
#pragma unroll
      for (int ct = 0; ct < 4; ++ct) B[ct] = *(const lx2*)(wb + ct * 1024 + base);
#pragma unroll
      for (int rt = 0; rt < 4; ++rt)
#pragma unroll
        for (int ct = 0; ct < 4; ++ct)
          acc[rt][ct] = __builtin_amdgcn_mfma_f32_16x16x32_fp8_fp8(A[rt][0], B[ct][0], acc[rt][ct], 0, 0, 0);
#pragma unroll
      for (int rt = 0; rt < 4; ++rt)
#pragma unroll
        for (int ct = 0; ct < 4; ++ct)
          acc[rt][ct] = __builtin_amdgcn_mfma_f32_16x16x32_fp8_fp8(A[rt][1], B[ct][1], acc[rt][ct], 0, 0, 0);
    }
  }
  __syncthreads();

  // ---- epilogue 1: dequant(1/256) + bias + relu -> fp8(x16) exchange ----
  {
    const float* bp = (wv < 8) ? (btb + wv * Dn) : (bsh + (wv - 8) * Dn);
    float bias[4];
#pragma unroll
    for (int ct = 0; ct < 4; ++ct) bias[ct] = bp[d0 + ct * 16 + r];
    char* ex = smem + SB + (wv << 12);
#pragma unroll
    for (int rt = 0; rt < 4; ++rt)
#pragma unroll
      for (int ct = 0; ct < 4; ++ct) {
        float v0 = fmaxf(acc[rt][ct][0] * 0.00390625f + bias[ct], 0.f) * 16.f;
        float v1 = fmaxf(acc[rt][ct][1] * 0.00390625f + bias[ct], 0.f) * 16.f;
        float v2 = fmaxf(acc[rt][ct][2] * 0.00390625f + bias[ct], 0.f) * 16.f;
        float v3 = fmaxf(acc[rt][ct][3] * 0.00390625f + bias[ct], 0.f) * 16.f;
        int col = ct * 16 + r;
        int off = (col << 6) + rt * 16 + g * 4;
        off ^= (col & 7) << 3;
        *(int*)(ex + off) = pk4fp8(v0, v1, v2, v3);
      }
  }
  __syncthreads();

  // ---- epilogue 2: gated combine ----
  if (tid < 512) {
    int col = tid & 63, q = tid >> 6;
    int exoff = ((col << 6) + (q << 3)) ^ ((col & 7) << 3);
    long v[12];
#pragma unroll
    for (int e = 0; e < 12; ++e)
      v[e] = *(const long*)(smem + SB + (e << 12) + exoff);
    unsigned short* os0 = (unsigned short*)(smem + OUTS);
    unsigned short* os1 = os0 + 64 * 72;
#pragma unroll
    for (int half = 0; half < 2; ++half) {
#pragma unroll
      for (int jj = 0; jj < 4; ++jj) {
        int row = (q << 3) + half * 4 + jj;
        const float* gp = (const float*)(smem + GSH + (row << 6));
        float4 ga = ((const float4*)gp)[0];
        float4 gb = ((const float4*)gp)[1];
        float4 gc = ((const float4*)gp)[2];
        float4 gd = ((const float4*)gp)[3];
        float f[12];
#pragma unroll
        for (int e = 0; e < 12; ++e) {
          unsigned w32 = (unsigned)(v[e] >> (half * 32));
          f[e] = __builtin_amdgcn_cvt_f32_fp8((int)(w32 >> (jj * 8)), 0);
        }
        float s0 = ga.x * f[0] + ga.y * f[1] + ga.z * f[2] + ga.w * f[3] +
                   gb.x * f[8] + gb.y * f[9] + gb.z * f[10] + gb.w * f[11];
        float s1 = gc.x * f[4] + gc.y * f[5] + gc.z * f[6] + gc.w * f[7] +
                   gd.x * f[8] + gd.y * f[9] + gd.z * f[10] + gd.w * f[11];
        os0[row * 72 + col] = f2bf(s0 * 0.0625f);
        os1[row * 72 + col] = f2bf(s1 * 0.0625f);
      }
    }
  }
  __syncthreads();

  // ---- epilogue 3: global writes ----
  if (tid < 512) {
    int row = tid >> 3, cq = tid & 7;
    const unsigned short* os0 = (const unsigned short*)(smem + OUTS) + row * 72 + cq * 8;
    const unsigned short* os1 = os0 + 64 * 72;
    ushort8 p0 = *(const ushort8*)os0, p1 = *(const ushort8*)os1;
    int b = b0 + row, d = d0 + cq * 8;
    if (MODE == 0) {
      float m[8];
      ushort8 pk;
#pragma unroll
      for (int u = 0; u < 8; ++u) {
        m[u] = 0.5f * (bf2f((unsigned short)p0[u]) + bf2f((unsigned short)p1[u]));
        pk[u] = f2bf(m[u]);
      }
      *(ushort8*)(outn + (size_t)b * Dn + d) = pk;
      int lk = d & 63;
      int ks = lk >> 5, g2 = (lk & 31) >> 3;
      int gq = g2 ^ ((row >> 1) & 3);
      int pos = (row << 6) + (gq << 4) + (ks << 3);
      int2 o8;
      o8.x = pk4fp8(m[0] * 16.f, m[1] * 16.f, m[2] * 16.f, m[3] * 16.f);
      o8.y = pk4fp8(m[4] * 16.f, m[5] * 16.f, m[6] * 16.f, m[7] * 16.f);
      *(int2*)(outt8 + (((size_t)dblk * 128 + bblk) << 12) + pos) = o8;
    } else {
      int kk2 = d >> 5;
      int nat = (row << 6) + ((d & 31) << 1);
      *(ushort8*)(outtb + (((size_t)(0 * 16 + kk2) * 128 + bblk) << 11) + (swz(nat) >> 1)) = p0;
      *(ushort8*)(outtb + (((size_t)(1 * 16 + kk2) * 128 + bblk) << 11) + (swz(nat) >> 1)) = p1;
    }
  }
}

// ============ fused MFMA tower (bf16) ============
#define TWBUF 36864
#define H1OFF 73728

__global__ __launch_bounds__(512) void tower_mfma(
    const unsigned short* __restrict__ toutT,
    const unsigned short* __restrict__ twbt1, const unsigned short* __restrict__ twbt2,
    const float* __restrict__ tb1,
    const float* __restrict__ bng, const float* __restrict__ bnb,
    const float* __restrict__ bnm, const float* __restrict__ bnv,
    const float* __restrict__ tb2, const float* __restrict__ tw3,
    const float* __restrict__ tb3, float* __restrict__ out) {
  __shared__ __align__(16) char smem[106496];
  int tid = threadIdx.x;
  int wv = tid >> 6, lane = tid & 63, r = lane & 15, g = lane >> 4;
  int blk = blockIdx.x;
  int bblk = blk >> 1, sub = blk & 1;
  int b0 = blk * 32;
  char* h1t = smem + H1OFF;

  int t1 = wv >> 2, hb = wv & 3;
  f32x4 acc[2][4];
#pragma unroll
  for (int i = 0; i < 2; ++i)
#pragma unroll
    for (int j = 0; j < 4; ++j) acc[i][j] = f32x4{0.f, 0.f, 0.f, 0.f};

  auto stage1 = [&](int t, char* lb) {
#pragma unroll
    for (int i = 0; i < 4; ++i)
      gload16((const char*)twbt1 + (size_t)t * 32768 + tid * 16 + i * 8192,
              lb + tid * 16 + i * 8192);
    if (tid < 256) {
      int tt = tid >> 7, off = (tid & 127) * 16;
      gload16((const char*)toutT + (((size_t)(tt * 16 + t) * 128 + bblk) << 12) + sub * 2048 + off,
              lb + 32768 + tt * 2048 + off);
    }
  };

  stage1(0, smem);
  __syncthreads();
  int cur = 0;
  for (int kk = 0; kk < 16; ++kk) {
    if (kk + 1 < 16) stage1(kk + 1, smem + (cur ^ 1) * TWBUF);
    {
      const char* lb = smem + cur * TWBUF;
      const char* wb = lb + (hb * 2 + t1) * 4096;
      const char* xb = lb + 32768 + t1 * 2048;
      short8 a[2], bfr[4];
#pragma unroll
      for (int rt = 0; rt < 2; ++rt)
        a[rt] = *(const short8*)(xb + swz(((rt * 16 + r) << 6) + (g << 4)));
#pragma unroll
      for (int ct = 0; ct < 4; ++ct)
        bfr[ct] = *(const short8*)(wb + swz(((ct * 16 + r) << 6) + (g << 4)));
#pragma unroll
      for (int rt = 0; rt < 2; ++rt)
#pragma unroll
        for (int ct = 0; ct < 4; ++ct)
          acc[rt][ct] = __builtin_amdgcn_mfma_f32_16x16x32_bf16(a[rt], bfr[ct], acc[rt][ct], 0, 0, 0);
    }
    __syncthreads();
    cur ^= 1;
  }

  {
#pragma unroll
    for (int ct = 0; ct < 4; ++ct) {
      int h = hb * 64 + ct * 16 + r;
      int idx = t1 * 256 + h;
      float inv = rsqrtf(bnv[idx] + 1e-5f) * bng[idx];
      float mu = bnm[idx], be = bnb[idx], bias = tb1[idx];
      int kk2 = h >> 5, kloc = h & 31;
      char* tile = h1t + (t1 * 8 + kk2) * 2048;
#pragma unroll
      for (int rt = 0; rt < 2; ++rt)
#pragma unroll
        for (int j = 0; j < 4; ++j) {
          int lr = rt * 16 + g * 4 + j;
          float v = acc[rt][ct][j] + bias;
          v = (v - mu) * inv + be;
          v = fmaxf(v, 0.f);
          *(unsigned short*)(tile + swz((lr << 6) + (kloc << 1))) = f2bf(v);
        }
    }
  }
  __syncthreads();

  float* h2x = (float*)smem;
  if (wv < 4) {
    int t2 = wv >> 1, hb2 = wv & 1;
    f32x4 acc2[2][4];
#pragma unroll
    for (int i = 0; i < 2; ++i)
#pragma unroll
      for (int j = 0; j < 4; ++j) acc2[i][j] = f32x4{0.f, 0.f, 0.f, 0.f};
    for (int kk = 0; kk < 8; ++kk) {
      const char* xb = h1t + (t2 * 8 + kk) * 2048;
      const char* wb = (const char*)twbt2 + ((kk * 2 + hb2) * 2 + t2) * 4096;
      short8 a[2], bfr[4];
#pragma unroll
      for (int rt = 0; rt < 2; ++rt)
        a[rt] = *(const short8*)(xb + swz(((rt * 16 + r) << 6) + (g << 4)));
#pragma unroll
      for (int ct = 0; ct < 4; ++ct)
        bfr[ct] = *(const short8*)(wb + swz(((ct * 16 + r) << 6) + (g << 4)));
#pragma unroll
      for (int rt = 0; rt < 2; ++rt)
#pragma unroll
        for (int ct = 0; ct < 4; ++ct)
          acc2[rt][ct] = __builtin_amdgcn_mfma_f32_16x16x32_bf16(a[rt], bfr[ct], acc2[rt][ct], 0, 0, 0);
    }
#pragma unroll
    for (int ct = 0; ct < 4; ++ct) {
      int col = hb2 * 64 + ct * 16 + r;
      float bias = tb2[t2 * 128 + col];
#pragma unroll
      for (int rt = 0; rt < 2; ++rt)
#pragma unroll
        for (int j = 0; j < 4; ++j) {
          int lr = rt * 16 + g * 4 + j;
          h2x[(t2 * 32 + lr) * 129 + col] = fmaxf(acc2[rt][ct][j] + bias, 0.f);
        }
    }
  }
  __syncthreads();

  float* lgs = (float*)(smem + 40960);
  if (tid < 64) {
    int t3 = tid >> 5, lr = tid & 31;
    const float* hr = h2x + (t3 * 32 + lr) * 129;
    const float* w3 = tw3 + t3 * 128;
    float s = 0.f;
#pragma unroll 8
    for (int i = 0; i < 128; ++i) s += hr[i] * w3[i];
    lgs[t3 * 32 + lr] = s + tb3[t3];
  }
  __syncthreads();
  if (tid < 32) {
    int b = b0 + tid;
    float ctr = 1.f / (1.f + expf(-lgs[tid]));
    float cvr = 1.f / (1.f + expf(-lgs[32 + tid]));
    float cc = ctr * cvr;
    out[b] = ctr;
    out[Bn + b] = cc;
    out[2 * Bn + b] = cc;
  }
}

// ============ launch ============
extern "C" void kernel_launch(void* const* d_in, const int* in_sizes, int n_in,
                              void* d_out, int out_size, void* d_ws, size_t ws_size,
                              hipStream_t stream) {
  const int* sparse   = (const int*)d_in[0];
  const float* dense  = (const float*)d_in[1];
  const float* emb    = (const float*)d_in[2];
  const float* dW     = (const float*)d_in[3];
  const float* db     = (const float*)d_in[4];
  const float* Wt[3]  = {(const float*)d_in[5],  (const float*)d_in[11], (const float*)d_in[17]};
  const float* btb[3] = {(const float*)d_in[6],  (const float*)d_in[12], (const float*)d_in[18]};
  const float* Wsh[3] = {(const float*)d_in[7],  (const float*)d_in[13], (const float*)d_in[19]};
  const float* bsh[3] = {(const float*)d_in[8],  (const float*)d_in[14], (const float*)d_in[20]};
  const float* Wg[3]  = {(const float*)d_in[9],  (const float*)d_in[15], (const float*)d_in[21]};
  const float* bg[3]  = {(const float*)d_in[10], (const float*)d_in[16], (const float*)d_in[22]};
  const float* tw1 = (const float*)d_in[23];
  const float* tb1 = (const float*)d_in[24];
  const float* bng = (const float*)d_in[25];
  const float* bnb = (const float*)d_in[26];
  const float* bnm = (const float*)d_in[27];
  const float* bnv = (const float*)d_in[28];
  const float* tw2 = (const float*)d_in[29];
  const float* tb2 = (const float*)d_in[30];
  const float* tw3 = (const float*)d_in[31];
  const float* tb3 = (const float*)d_in[32];

  // workspace layout
  unsigned short* x0n = (unsigned short*)d_ws;                    // bf16 8192x960
  unsigned short* x1n = x0n + (size_t)Bn * 960;                   // bf16 8192x512
  unsigned short* toutT = x1n + (size_t)Bn * 512;                 // bf16 tower tiles
  float* gatesB = (float*)(toutT + (size_t)Bn * 1024);            // f32 8192x16
  unsigned short* twbt1 = (unsigned short*)(gatesB + (size_t)Bn * 16);
  unsigned short* twbt2 = twbt1 + (size_t)2 * 512 * 256;
  unsigned char* x0t = (unsigned char*)(twbt2 + (size_t)2 * 256 * 128);  // fp8 8192x960
  unsigned char* x1t = x0t + (size_t)Bn * 960;                    // fp8 8192x512
  unsigned char* Wbt = x1t + (size_t)Bn * 512;                    // fp8 tiles, all 3 layers (12.2MB)
  unsigned short* wgb = (unsigned short*)(Wbt + (size_t)12189696);
  unsigned short* wgb0 = wgb;
  unsigned short* wgb1 = wgb0 + (size_t)16 * 960;
  unsigned short* wgb2 = wgb1 + (size_t)16 * 512;
  unsigned short* x2n = x0n;
  unsigned char* x2t = x0t;

  conv_tw<512, 256><<<dim3(16, 4, 2), 256, 0, stream>>>(tw1, twbt1);
  conv_tw<256, 128><<<dim3(8, 2, 2), 256, 0, stream>>>(tw2, twbt2);
  conv_wg_all<<<dim3(15, 16, 3), 64, 0, stream>>>(Wg[0], Wg[1], Wg[2], wgb);
  conv_w_all<<<dim3(15, 8, 36), 256, 0, stream>>>(Wt[0], Wsh[0], Wt[1], Wsh[1],
                                                  Wt[2], Wsh[2], Wbt);

  embed_kernel<<<Bn / 4, 256, 0, stream>>>(sparse, dense, emb, dW, db, wgb0, bg[0],
                                           x0n, x0t, gatesB);
  ple_mfma<960, 0><<<1024, 768, 0, stream>>>(x0t, gatesB, Wbt, btb[0], bsh[0], x1n, x1t, nullptr);

  gate_kernel<512><<<Bn / 4, 256, 0, stream>>>(x1n, wgb1, bg[1], gatesB);
  ple_mfma<512, 0><<<1024, 768, 0, stream>>>(x1t, gatesB, Wbt + WBT_L1_OFF, btb[1], bsh[1],
                                             x2n, x2t, nullptr);

  gate_kernel<512><<<Bn / 4, 256, 0, stream>>>(x2n, wgb2, bg[2], gatesB);
  ple_mfma<512, 1><<<1024, 768, 0, stream>>>(x2t, gatesB, Wbt + WBT_L2_OFF, btb[2], bsh[2],
                                             nullptr, nullptr, toutT);

  tower_mfma<<<256, 512, 0, stream>>>(toutT, twbt1, twbt2, tb1, bng, bnb, bnm, bnv,
                                      tb2, tw3, tb3, (float*)d_out);
}